// Round 2
// baseline (2276.874 us; speedup 1.0000x reference)
//
#include <hip/hip_runtime.h>

#define NSTEPS 8
#define DT (1.0f / NSTEPS)

// ---------------------------------------------------------------------------
// ws layout (float offsets):
//  Gt    @ 0        [512*512]   Gt[k*512+j] = W2[j,k]*sum_m W1[m,j]W3[k,m]
//  W2T   @ 262144   [512*512]   W2T[k*512+j] = W2[j*512+k]
//  h1    @ 524288   [512*512]   post-tanh
//  h2    @ 786432   [512*512]   post-tanh
//  parts @ 1048576  [8*512*512] pre-activation j-partials of layer2
//  xb    @ 3145728  [512*64]
//  kx    @ 3178496  [4*512*64]
//  tr    @ 3309568  [4*512]
//  ld    @ 3311616  [512]
// ---------------------------------------------------------------------------

__global__ __launch_bounds__(256) void pre_kernel(
    const float* __restrict__ W1, const float* __restrict__ W2,
    const float* __restrict__ W3, float* __restrict__ Gt,
    float* __restrict__ W2T) {
  int gid = blockIdx.x * 256 + threadIdx.x;  // 262144
  int k = gid >> 9, j = gid & 511;
  float s = 0.f;
#pragma unroll
  for (int m = 0; m < 64; ++m) s = fmaf(W1[m * 512 + j], W3[k * 64 + m], s);
  float w = W2[j * 512 + k];
  W2T[gid] = w;
  Gt[gid] = s * w;
}

__global__ __launch_bounds__(256) void init_kernel(
    const float* __restrict__ x, float* __restrict__ xb, float* __restrict__ tr,
    float* __restrict__ ld) {
  int gid = blockIdx.x * 256 + threadIdx.x;
  if (gid < 512 * 64) xb[gid] = x[gid];
  if (gid < 4 * 512) tr[gid] = 0.f;
  if (gid < 512) ld[gid] = 0.f;
}

// block = batch row. Optionally folds the RK4 combine of the previous step.
// h1[row][j] = tanh( sum_i xin_i W1[i,j] + b1[j] + t*W1[64,j] ), xin = xb + c*kprev
__global__ __launch_bounds__(256, 2) void l1_kernel(
    float* __restrict__ xb, const float* __restrict__ kprev, float c, float t,
    const float* __restrict__ W1, const float* __restrict__ b1,
    float* __restrict__ h1, float* __restrict__ kxz, int docomb,
    const float* __restrict__ k1, const float* __restrict__ k2,
    const float* __restrict__ k3, const float* __restrict__ k4,
    float* __restrict__ ld, float* __restrict__ tr) {
  __shared__ float xinl[64];
  int row = blockIdx.x, tid = threadIdx.x;
  if (tid < 64) {
    int base = row * 64 + tid;
    if (docomb) {  // combine substages have c == 0
      float xv = xb[base] + (DT / 6.f) * (k1[base] + 2.f * k2[base] +
                                          2.f * k3[base] + k4[base]);
      xb[base] = xv;
      xinl[tid] = xv;
    } else {
      xinl[tid] = xb[base] + c * kprev[base];
    }
    kxz[base] = 0.f;  // zero this substage's kx accumulator (after reads above)
  }
  if (docomb && tid == 64) {
    float lv = ld[row] + (DT / 6.f) * (tr[row] + 2.f * tr[512 + row] +
                                       2.f * tr[1024 + row] + tr[1536 + row]);
    ld[row] = lv;
    tr[row] = 0.f;
    tr[512 + row] = 0.f;
    tr[1024 + row] = 0.f;
    tr[1536 + row] = 0.f;
  }
  __syncthreads();
#pragma unroll
  for (int o = 0; o < 2; ++o) {
    int j = tid + o * 256;
    float acc = b1[j] + t * W1[64 * 512 + j];
#pragma unroll 8
    for (int i = 0; i < 64; ++i) acc = fmaf(xinl[i], W1[i * 512 + j], acc);
    h1[row * 512 + j] = tanhf(acc);
  }
}

// layer2 partial GEMM: 512 blocks = (8 b-tiles x 8 k-tiles x 8 j-quarters),
// tile 64x64, K=64 per block, 8 accumulators/thread.
__global__ __launch_bounds__(512, 4) void l2_kernel(
    const float* __restrict__ h1, const float* __restrict__ W2T,
    float* __restrict__ part) {
  int bx = blockIdx.x;
  int b0 = (bx >> 6) * 64, k0 = ((bx >> 3) & 7) * 64, j0 = (bx & 7) * 64;
  int tid = threadIdx.x;
  int kl = tid & 15, rg = tid >> 4;
  int r0 = b0 + rg * 2;
  int kc = k0 + kl * 4;
  const float* ha = h1 + r0 * 512 + j0;
  const float* hb = ha + 512;
  const float* w0 = W2T + (kc + 0) * 512 + j0;
  const float* w1 = W2T + (kc + 1) * 512 + j0;
  const float* w2 = W2T + (kc + 2) * 512 + j0;
  const float* w3 = W2T + (kc + 3) * 512 + j0;
  float a00 = 0, a01 = 0, a02 = 0, a03 = 0, a10 = 0, a11 = 0, a12 = 0, a13 = 0;
  for (int jj = 0; jj < 64; jj += 4) {
    float4 xa = *(const float4*)(ha + jj);
    float4 xc = *(const float4*)(hb + jj);
    float4 q0 = *(const float4*)(w0 + jj);
    float4 q1 = *(const float4*)(w1 + jj);
    float4 q2 = *(const float4*)(w2 + jj);
    float4 q3 = *(const float4*)(w3 + jj);
    a00 = fmaf(xa.x, q0.x, fmaf(xa.y, q0.y, fmaf(xa.z, q0.z, fmaf(xa.w, q0.w, a00))));
    a01 = fmaf(xa.x, q1.x, fmaf(xa.y, q1.y, fmaf(xa.z, q1.z, fmaf(xa.w, q1.w, a01))));
    a02 = fmaf(xa.x, q2.x, fmaf(xa.y, q2.y, fmaf(xa.z, q2.z, fmaf(xa.w, q2.w, a02))));
    a03 = fmaf(xa.x, q3.x, fmaf(xa.y, q3.y, fmaf(xa.z, q3.z, fmaf(xa.w, q3.w, a03))));
    a10 = fmaf(xc.x, q0.x, fmaf(xc.y, q0.y, fmaf(xc.z, q0.z, fmaf(xc.w, q0.w, a10))));
    a11 = fmaf(xc.x, q1.x, fmaf(xc.y, q1.y, fmaf(xc.z, q1.z, fmaf(xc.w, q1.w, a11))));
    a12 = fmaf(xc.x, q2.x, fmaf(xc.y, q2.y, fmaf(xc.z, q2.z, fmaf(xc.w, q2.w, a12))));
    a13 = fmaf(xc.x, q3.x, fmaf(xc.y, q3.y, fmaf(xc.z, q3.z, fmaf(xc.w, q3.w, a13))));
  }
  float* pout = part + (bx & 7) * 262144 + r0 * 512 + kc;
  *(float4*)pout = make_float4(a00, a01, a02, a03);
  *(float4*)(pout + 512) = make_float4(a10, a11, a12, a13);
}

// h2 = tanh(b2 + sum of 8 j-partials)
__global__ __launch_bounds__(512, 4) void act2_kernel(
    const float* __restrict__ part, const float* __restrict__ b2,
    float* __restrict__ h2) {
  int gid = blockIdx.x * 512 + threadIdx.x;
#pragma unroll
  for (int o = 0; o < 2; ++o) {
    int e = gid + o * 131072;
    float s = b2[e & 511];
#pragma unroll
    for (int q = 0; q < 8; ++q) s += part[q * 262144 + e];
    h2[e] = tanhf(s);
  }
}

// trace partial GEMM + L3 partial. 512 blocks = (8 b x 8 j x 8 kq).
// trace: w[b][j] = sum_kk (1-h2^2) Gt[kk][j];  tr[b] -= sum_j (1-h1^2) w
// L3:    kx[b][m] += sum_kk h2 W3[kk][m]   (m-slice of 8 per j-tile index)
__global__ __launch_bounds__(512, 4) void tr3_kernel(
    const float* __restrict__ h1, const float* __restrict__ h2,
    const float* __restrict__ Gt, const float* __restrict__ W3,
    const float* __restrict__ b3, float* __restrict__ kx,
    float* __restrict__ trs) {
  int bx = blockIdx.x;
  int bt = bx >> 6, jt = (bx >> 3) & 7, kq = bx & 7;
  int b0 = bt * 64, j0 = jt * 64, kb = kq * 64;
  int tid = threadIdx.x;
  int jl = tid & 15, rg = tid >> 4;
  int r0 = b0 + rg * 2;
  int jc = j0 + jl * 4;
  float a00 = 0, a01 = 0, a02 = 0, a03 = 0, a10 = 0, a11 = 0, a12 = 0, a13 = 0;
  const float* ha = h2 + r0 * 512 + kb;
  const float* hb = ha + 512;
  for (int kk = 0; kk < 64; kk += 4) {
    float4 xa = *(const float4*)(ha + kk);
    float4 xc = *(const float4*)(hb + kk);
    float va0 = 1.f - xa.x * xa.x, va1 = 1.f - xa.y * xa.y;
    float va2 = 1.f - xa.z * xa.z, va3 = 1.f - xa.w * xa.w;
    float vb0 = 1.f - xc.x * xc.x, vb1 = 1.f - xc.y * xc.y;
    float vb2 = 1.f - xc.z * xc.z, vb3 = 1.f - xc.w * xc.w;
    float4 g0 = *(const float4*)(Gt + (kb + kk + 0) * 512 + jc);
    float4 g1 = *(const float4*)(Gt + (kb + kk + 1) * 512 + jc);
    float4 g2 = *(const float4*)(Gt + (kb + kk + 2) * 512 + jc);
    float4 g3 = *(const float4*)(Gt + (kb + kk + 3) * 512 + jc);
    a00 = fmaf(va0, g0.x, fmaf(va1, g1.x, fmaf(va2, g2.x, fmaf(va3, g3.x, a00))));
    a01 = fmaf(va0, g0.y, fmaf(va1, g1.y, fmaf(va2, g2.y, fmaf(va3, g3.y, a01))));
    a02 = fmaf(va0, g0.z, fmaf(va1, g1.z, fmaf(va2, g2.z, fmaf(va3, g3.z, a02))));
    a03 = fmaf(va0, g0.w, fmaf(va1, g1.w, fmaf(va2, g2.w, fmaf(va3, g3.w, a03))));
    a10 = fmaf(vb0, g0.x, fmaf(vb1, g1.x, fmaf(vb2, g2.x, fmaf(vb3, g3.x, a10))));
    a11 = fmaf(vb0, g0.y, fmaf(vb1, g1.y, fmaf(vb2, g2.y, fmaf(vb3, g3.y, a11))));
    a12 = fmaf(vb0, g0.z, fmaf(vb1, g1.z, fmaf(vb2, g2.z, fmaf(vb3, g3.z, a12))));
    a13 = fmaf(vb0, g0.w, fmaf(vb1, g1.w, fmaf(vb2, g2.w, fmaf(vb3, g3.w, a13))));
  }
  float4 u1a = *(const float4*)(h1 + r0 * 512 + jc);
  float4 u1b = *(const float4*)(h1 + (r0 + 1) * 512 + jc);
  float pa = a00 * (1.f - u1a.x * u1a.x) + a01 * (1.f - u1a.y * u1a.y) +
             a02 * (1.f - u1a.z * u1a.z) + a03 * (1.f - u1a.w * u1a.w);
  float pb = a10 * (1.f - u1b.x * u1b.x) + a11 * (1.f - u1b.y * u1b.y) +
             a12 * (1.f - u1b.z * u1b.z) + a13 * (1.f - u1b.w * u1b.w);
  pa += __shfl_xor(pa, 1); pa += __shfl_xor(pa, 2);
  pa += __shfl_xor(pa, 4); pa += __shfl_xor(pa, 8);
  pb += __shfl_xor(pb, 1); pb += __shfl_xor(pb, 2);
  pb += __shfl_xor(pb, 4); pb += __shfl_xor(pb, 8);
  if (jl == 0) {
    atomicAdd(trs + r0, -pa);
    atomicAdd(trs + r0 + 1, -pb);
  }
  // ---- L3 slice: rows b0..b0+63, cols m = jt*8..jt*8+7, K-span kb..kb+63
  int row = b0 + (tid >> 3);
  int m = jt * 8 + (tid & 7);
  float a3 = (kq == 0) ? b3[m] : 0.f;
  const float* hr = h2 + row * 512 + kb;
#pragma unroll 4
  for (int kk = 0; kk < 64; ++kk) a3 = fmaf(hr[kk], W3[(kb + kk) * 64 + m], a3);
  atomicAdd(kx + row * 64 + m, a3);
}

__global__ __launch_bounds__(256) void final_kernel(
    const float* __restrict__ xb, const float* __restrict__ k1,
    const float* __restrict__ k2, const float* __restrict__ k3,
    const float* __restrict__ k4, const float* __restrict__ ld,
    const float* __restrict__ tr, float* __restrict__ out) {
  int gid = blockIdx.x * 256 + threadIdx.x;
  if (gid < 32768) {
    out[gid] = xb[gid] + (DT / 6.f) * (k1[gid] + 2.f * k2[gid] +
                                       2.f * k3[gid] + k4[gid]);
  } else if (gid < 33280) {
    int b = gid - 32768;
    out[32768 + b] = ld[b] + (DT / 6.f) * (tr[b] + 2.f * tr[512 + b] +
                                           2.f * tr[1024 + b] + tr[1536 + b]);
  }
}

extern "C" void kernel_launch(void* const* d_in, const int* in_sizes, int n_in,
                              void* d_out, int out_size, void* d_ws,
                              size_t ws_size, hipStream_t stream) {
  const float* x = (const float*)d_in[0];
  const float* W1 = (const float*)d_in[1];
  const float* b1 = (const float*)d_in[2];
  const float* W2 = (const float*)d_in[3];
  const float* b2 = (const float*)d_in[4];
  const float* W3 = (const float*)d_in[5];
  const float* b3 = (const float*)d_in[6];
  float* out = (float*)d_out;
  float* ws = (float*)d_ws;

  float* Gt = ws;
  float* W2T = ws + 262144;
  float* h1 = ws + 524288;
  float* h2 = ws + 786432;
  float* parts = ws + 1048576;          // 8 * 262144
  float* xb = ws + 3145728;
  float* kx0 = ws + 3178496;
  float* kx1 = ws + 3211264;
  float* kx2 = ws + 3244032;
  float* kx3 = ws + 3276800;
  float* tr = ws + 3309568;             // 4 * 512
  float* ld = ws + 3311616;             // 512
  float* kxs[4] = {kx0, kx1, kx2, kx3};

  pre_kernel<<<1024, 256, 0, stream>>>(W1, W2, W3, Gt, W2T);
  init_kernel<<<128, 256, 0, stream>>>(x, xb, tr, ld);

  for (int s = 0; s < NSTEPS; ++s) {
    float t0 = s * DT;
    const float cs[4] = {0.f, 0.5f * DT, 0.5f * DT, DT};
    const float ts[4] = {t0, t0 + 0.5f * DT, t0 + 0.5f * DT, t0 + DT};
    for (int g = 0; g < 4; ++g) {
      const float* kprev = g ? kxs[g - 1] : xb;
      int docomb = (g == 0 && s > 0) ? 1 : 0;
      l1_kernel<<<512, 256, 0, stream>>>(xb, kprev, cs[g], ts[g], W1, b1, h1,
                                         kxs[g], docomb, kx0, kx1, kx2, kx3,
                                         ld, tr);
      l2_kernel<<<512, 512, 0, stream>>>(h1, W2T, parts);
      act2_kernel<<<256, 512, 0, stream>>>(parts, b2, h2);
      tr3_kernel<<<512, 512, 0, stream>>>(h1, h2, Gt, W3, b3, kxs[g],
                                          tr + g * 512);
    }
  }
  final_kernel<<<130, 256, 0, stream>>>(xb, kx0, kx1, kx2, kx3, ld, tr, out);
}

// Round 3
// 952.498 us; speedup vs baseline: 2.3904x; 2.3904x over previous
//
#include <hip/hip_runtime.h>

#define NSTEPS 8
#define DT (1.0f / NSTEPS)

typedef __bf16 bfv8 __attribute__((ext_vector_type(8)));
typedef float f32x4 __attribute__((ext_vector_type(4)));

__device__ __forceinline__ float fast_tanh(float x) {
  // tanh(x) = 1 - 2/(exp(2x)+1); exp via fast path, rcp ~1ulp (fine for bf16)
  float e = __expf(2.f * x);
  return 1.f - 2.f * __builtin_amdgcn_rcpf(e + 1.f);
}

// ---------------------------------------------------------------------------
// ws (bytes): GtT_b[512][512] @0 (512K), W2T_b[512][512] @512K,
//             W1T_b[512][64] @1M, W3T_b[64][512] @1M+64K   (all bf16)
// GtT[j][k] = W2[j][k] * sum_m W1[m][j] W3[k][m]
// ---------------------------------------------------------------------------
__global__ __launch_bounds__(256) void pre_kernel(
    const float* __restrict__ W1, const float* __restrict__ W2,
    const float* __restrict__ W3, __bf16* __restrict__ GtT,
    __bf16* __restrict__ W2T, __bf16* __restrict__ W1T,
    __bf16* __restrict__ W3T) {
  int gid = blockIdx.x * 256 + threadIdx.x;
  if (gid < 262144) {            // GtT[j*512+k], coalesced store
    int j = gid >> 9, k = gid & 511;
    float s = 0.f;
#pragma unroll
    for (int m = 0; m < 64; ++m)
      s = fmaf(W1[m * 512 + j], W3[k * 64 + m], s);
    GtT[gid] = (__bf16)(s * W2[j * 512 + k]);
  } else if (gid < 524288) {     // W2T[k*512+j] = W2[j][k]
    int g = gid - 262144;
    int k = g >> 9, j = g & 511;
    W2T[g] = (__bf16)W2[j * 512 + k];
  } else if (gid < 557056) {     // W1T[j*64+i] = W1[i][j]
    int g = gid - 524288;
    int j = g >> 6, i = g & 63;
    W1T[g] = (__bf16)W1[i * 512 + j];
  } else if (gid < 589824) {     // W3T[m*512+k] = W3[k][m]
    int g = gid - 557056;
    int m = g >> 9, k = g & 511;
    W3T[g] = (__bf16)W3[k * 64 + m];
  }
}

// ---------------------------------------------------------------------------
// Persistent CNF integrator: 32 blocks x 16 rows, 512 threads (8 waves).
// Whole 8-step RK4 in one kernel; weights streamed bf16 from L2 each eval.
// MFMA 16x16x32 bf16: A row = lane&15, k = (lane>>4)*8+i;
//                     B col = lane&15, same k;  D col = lane&15,
//                     row = (lane>>4)*4 + reg.   (m89-verified family)
// ---------------------------------------------------------------------------
__global__ __launch_bounds__(512, 2) void cnf_kernel(
    const float* __restrict__ x, const float* __restrict__ W1,
    const float* __restrict__ b1, const float* __restrict__ b2,
    const float* __restrict__ b3, const __bf16* __restrict__ GtT,
    const __bf16* __restrict__ W2T, const __bf16* __restrict__ W1T,
    const __bf16* __restrict__ W3T, float* __restrict__ out) {
  __shared__ __bf16 h1s[16 * 512];   // XOR-swizzled: byte ^= (row&7)<<4
  __shared__ __bf16 h2s[16 * 512];
  __shared__ __bf16 vs[16 * 512];    // 1 - h2^2
  __shared__ __bf16 xins[16 * 64];
  __shared__ float xbs[16 * 64];
  __shared__ float kcur[16 * 64];
  __shared__ float kacc[16 * 64];
  __shared__ float trbuf[16];
  __shared__ float ldv[16];
  __shared__ float ldacc[16];

  const int tid = threadIdx.x;
  const int lane = tid & 63;
  const int w = tid >> 6;    // wave 0..7
  const int lr = lane & 15;  // A-row / B-col / D-col lane index
  const int lq = lane >> 4;  // k-quad
  const int rowbase = blockIdx.x * 16;

  for (int e = tid; e < 1024; e += 512) {
    float xv = x[(rowbase + (e >> 6)) * 64 + (e & 63)];
    xbs[e] = xv;
    kacc[e] = 0.f;
    xins[e] = (__bf16)xv;
  }
  if (tid < 16) { trbuf[tid] = 0.f; ldv[tid] = 0.f; ldacc[tid] = 0.f; }
  __syncthreads();

  for (int ev = 0; ev < 4 * NSTEPS; ++ev) {
    const int s = ev >> 2, g = ev & 3;
    const float t = s * DT + ((g == 0) ? 0.f : (g == 3) ? DT : 0.5f * DT);

    // ---------------- L1: h1 = tanh([xin,t] @ W1 + b1) ----------------
    {
      bfv8 a0 = *(const bfv8*)&xins[lr * 64 + lq * 8];
      bfv8 a1 = *(const bfv8*)&xins[lr * 64 + 32 + lq * 8];
#pragma unroll
      for (int n = 0; n < 4; ++n) {
        const int col = (w * 4 + n) * 16 + lr;
        const float cinit = b1[col] + t * W1[64 * 512 + col];
        f32x4 C = {cinit, cinit, cinit, cinit};
        const __bf16* brow = W1T + col * 64 + lq * 8;
        C = __builtin_amdgcn_mfma_f32_16x16x32_bf16(a0, *(const bfv8*)brow, C, 0, 0, 0);
        C = __builtin_amdgcn_mfma_f32_16x16x32_bf16(a1, *(const bfv8*)(brow + 32), C, 0, 0, 0);
#pragma unroll
        for (int r = 0; r < 4; ++r) {
          const int row = lq * 4 + r;
          const int boff = row * 1024 + ((col * 2) ^ ((row & 7) << 4));
          *(__bf16*)((char*)h1s + boff) = (__bf16)fast_tanh(C[r]);
        }
      }
    }
    __syncthreads();

    // ---------------- L2: h2 = tanh(h1 @ W2 + b2); v = 1-h2^2 ----------
    bfv8 A[16];
    {
#pragma unroll
      for (int c = 0; c < 16; ++c) {
        const int boff = lr * 1024 + ((c * 64 + lq * 16) ^ ((lr & 7) << 4));
        A[c] = *(const bfv8*)((char*)h1s + boff);
      }
#pragma unroll
      for (int n = 0; n < 4; ++n) {
        const int col = (w * 4 + n) * 16 + lr;
        const float cinit = b2[col];
        f32x4 C = {cinit, cinit, cinit, cinit};
        const __bf16* brow = W2T + col * 512 + lq * 8;
#pragma unroll
        for (int c = 0; c < 16; ++c)
          C = __builtin_amdgcn_mfma_f32_16x16x32_bf16(
              A[c], *(const bfv8*)(brow + c * 32), C, 0, 0, 0);
#pragma unroll
        for (int r = 0; r < 4; ++r) {
          const int row = lq * 4 + r;
          const float tv = fast_tanh(C[r]);
          const int boff = row * 1024 + ((col * 2) ^ ((row & 7) << 4));
          *(__bf16*)((char*)h2s + boff) = (__bf16)tv;
          *(__bf16*)((char*)vs + boff) = (__bf16)(1.f - tv * tv);
        }
      }
    }
    __syncthreads();

    // ------- TR: w = v @ GtT^T; tr[b] += sum_j u[b][j] w[b][j] ---------
    {
#pragma unroll
      for (int c = 0; c < 16; ++c) {
        const int boff = lr * 1024 + ((c * 64 + lq * 16) ^ ((lr & 7) << 4));
        A[c] = *(const bfv8*)((char*)vs + boff);
      }
      float p[4] = {0.f, 0.f, 0.f, 0.f};
#pragma unroll
      for (int n = 0; n < 4; ++n) {
        const int col = (w * 4 + n) * 16 + lr;  // j
        f32x4 C = {0.f, 0.f, 0.f, 0.f};
        const __bf16* brow = GtT + col * 512 + lq * 8;
#pragma unroll
        for (int c = 0; c < 16; ++c)
          C = __builtin_amdgcn_mfma_f32_16x16x32_bf16(
              A[c], *(const bfv8*)(brow + c * 32), C, 0, 0, 0);
#pragma unroll
        for (int r = 0; r < 4; ++r) {
          const int row = lq * 4 + r;
          const int boff = row * 1024 + ((col * 2) ^ ((row & 7) << 4));
          const float h1v = (float)*(const __bf16*)((char*)h1s + boff);
          p[r] += C[r] * (1.f - h1v * h1v);
        }
      }
#pragma unroll
      for (int r = 0; r < 4; ++r) {
        p[r] += __shfl_xor(p[r], 1);
        p[r] += __shfl_xor(p[r], 2);
        p[r] += __shfl_xor(p[r], 4);
        p[r] += __shfl_xor(p[r], 8);
      }
      if (lr == 0) {
#pragma unroll
        for (int r = 0; r < 4; ++r) atomicAdd(&trbuf[lq * 4 + r], p[r]);
      }
    }

    // ---------------- L3 (waves 0..3): kcur = h2 @ W3 + b3 -------------
    if (w < 4) {
#pragma unroll
      for (int c = 0; c < 16; ++c) {
        const int boff = lr * 1024 + ((c * 64 + lq * 16) ^ ((lr & 7) << 4));
        A[c] = *(const bfv8*)((char*)h2s + boff);
      }
      const int col = w * 16 + lr;  // m in [0,64)
      const float cinit = b3[col];
      f32x4 C = {cinit, cinit, cinit, cinit};
      const __bf16* brow = W3T + col * 512 + lq * 8;
#pragma unroll
      for (int c = 0; c < 16; ++c)
        C = __builtin_amdgcn_mfma_f32_16x16x32_bf16(
            A[c], *(const bfv8*)(brow + c * 32), C, 0, 0, 0);
#pragma unroll
      for (int r = 0; r < 4; ++r) kcur[(lq * 4 + r) * 64 + col] = C[r];
    }
    __syncthreads();

    // ---------------- combine / advance --------------------------------
    {
      const float cnext = (g == 2) ? DT : 0.5f * DT;  // used when g<3
      const float wg = (g == 0) ? 1.f : 2.f;
      for (int e = tid; e < 1024; e += 512) {
        const float kv = kcur[e];
        if (g < 3) {
          kacc[e] += wg * kv;
          xins[e] = (__bf16)(xbs[e] + cnext * kv);
        } else {
          const float xn = xbs[e] + (DT / 6.f) * (kacc[e] + kv);
          xbs[e] = xn;
          kacc[e] = 0.f;
          xins[e] = (__bf16)xn;
        }
      }
      if (tid < 16) {
        const float tv = trbuf[tid];
        trbuf[tid] = 0.f;
        if (g < 3) {
          ldacc[tid] += wg * tv;
        } else {
          ldv[tid] -= (DT / 6.f) * (ldacc[tid] + tv);
          ldacc[tid] = 0.f;
        }
      }
    }
    __syncthreads();
  }

  for (int e = tid; e < 1024; e += 512)
    out[(rowbase + (e >> 6)) * 64 + (e & 63)] = xbs[e];
  if (tid < 16) out[512 * 64 + rowbase + tid] = ldv[tid];
}

extern "C" void kernel_launch(void* const* d_in, const int* in_sizes, int n_in,
                              void* d_out, int out_size, void* d_ws,
                              size_t ws_size, hipStream_t stream) {
  const float* x = (const float*)d_in[0];
  const float* W1 = (const float*)d_in[1];
  const float* b1 = (const float*)d_in[2];
  const float* W2 = (const float*)d_in[3];
  const float* b2 = (const float*)d_in[4];
  const float* W3 = (const float*)d_in[5];
  const float* b3 = (const float*)d_in[6];
  float* out = (float*)d_out;
  char* ws = (char*)d_ws;

  __bf16* GtT = (__bf16*)(ws);
  __bf16* W2T = (__bf16*)(ws + (512 << 10));
  __bf16* W1T = (__bf16*)(ws + (1024 << 10));
  __bf16* W3T = (__bf16*)(ws + (1088 << 10));

  pre_kernel<<<2304, 256, 0, stream>>>(W1, W2, W3, GtT, W2T, W1T, W3T);
  cnf_kernel<<<32, 512, 0, stream>>>(x, W1, b1, b2, b3, GtT, W2T, W1T, W3T,
                                     out);
}